// Round 2
// baseline (5435.555 us; speedup 1.0000x reference)
//
#include <hip/hip_runtime.h>
#include <hip/hip_bf16.h>

typedef unsigned short ushort_t;
typedef unsigned int uint_t;
typedef _Float16 h2v __attribute__((ext_vector_type(2)));

#define N_NOTES 2000

__device__ __forceinline__ float sigm(float x) { return 1.0f / (1.0f + __expf(-x)); }
__device__ __forceinline__ float tanhc(float x) {
    x = fminf(fmaxf(x, -15.f), 15.f);
    float e = __expf(2.f * x);
    return (e - 1.f) / (e + 1.f);
}

#if __has_builtin(__builtin_amdgcn_fdot2)
__device__ __forceinline__ float fdot2f(uint_t a, uint_t b, float c) {
    return __builtin_amdgcn_fdot2(__builtin_bit_cast(h2v, a), __builtin_bit_cast(h2v, b), c, false);
}
#else
__device__ __forceinline__ float fdot2f(uint_t a, uint_t b, float c) {
    h2v x = __builtin_bit_cast(h2v, a), y = __builtin_bit_cast(h2v, b);
    return c + (float)x[0] * (float)y[0] + (float)x[1] * (float)y[1];
}
#endif

// ---------------- perform_z = relu(exp_W @ perf + exp_b) ----------------
__global__ __launch_bounds__(64) void pz_kernel(const float* __restrict__ expW,
                                                const float* __restrict__ expb,
                                                const float* __restrict__ perf,
                                                float* __restrict__ pz) {
    int t = threadIdx.x;
    float acc = expb[t];
#pragma unroll
    for (int k = 0; k < 16; k++) acc += expW[t * 16 + k] * perf[k];
    pz[t] = fmaxf(acc, 0.f);
}

// ---------------- opre[i][j]: known-input part of o-LSTM preact (incl fc_b fold) ----------------
__global__ __launch_bounds__(512) void opre_kernel(
    const float* __restrict__ oWih, const float* __restrict__ obih, const float* __restrict__ obhh,
    const float* __restrict__ ne, const float* __restrict__ be, const float* __restrict__ me,
    const float* __restrict__ fcb, const float* __restrict__ pz,
    const int* __restrict__ bn, const int* __restrict__ mn, float* __restrict__ opre) {
    const int i = blockIdx.x, j = threadIdx.x;
    const int cb = bn[i] - bn[0], cm = mn[i] - mn[0];
    const float* w = oWih + j * 715;
    float acc = obih[j] + obhh[j];
    const float* x0 = ne + i * 256;
#pragma unroll 8
    for (int k = 0; k < 256; k++) acc += w[k] * x0[k];
    const float* x1 = be + cb * 256;
#pragma unroll 8
    for (int k = 0; k < 256; k++) acc += w[256 + k] * x1[k];
    const float* x2 = me + cm * 128;
#pragma unroll 8
    for (int k = 0; k < 128; k++) acc += w[512 + k] * x2[k];
#pragma unroll
    for (int r = 0; r < 10; r++) acc += w[641 + r] * fcb[r];
#pragma unroll 8
    for (int k = 0; k < 64; k++) acc += w[651 + k] * pz[k];
    opre[i * 512 + j] = acc;
}

// ---------------- tpre[i][j]: known-input part of t-LSTM preact (boundary notes only) ----------------
__global__ __launch_bounds__(512) void tpre_kernel(
    const float* __restrict__ tWih, const float* __restrict__ tbih, const float* __restrict__ tbhh,
    const float* __restrict__ be, const float* __restrict__ me, const float* __restrict__ ri,
    const float* __restrict__ pz, const int* __restrict__ bn, const int* __restrict__ mn,
    float* __restrict__ tpre) {
    const int i = blockIdx.x;
    if (i > 0 && bn[i] == bn[i - 1]) return;  // not a beat boundary: never read
    const int j = threadIdx.x;
    const int cb = bn[i] - bn[0], cm = mn[i] - mn[0];
    const float* w = tWih + j * 467;
    float acc = tbih[j] + tbhh[j];
    const float* x0 = be + cb * 256;
#pragma unroll 8
    for (int k = 0; k < 256; k++) acc += w[k] * x0[k];
    const float* x1 = me + cm * 128;
#pragma unroll 8
    for (int k = 0; k < 128; k++) acc += w[256 + k] * x1[k];
    const float* x2 = ri + cb * 8;
#pragma unroll
    for (int k = 0; k < 8; k++) acc += w[385 + k] * x2[k];
#pragma unroll 8
    for (int k = 0; k < 64; k++) acc += w[403 + k] * pz[k];
    tpre[i * 512 + j] = acc;
}

// ---------------- the 2000-step serial scan: one 512-thread workgroup ----------------
__global__ __launch_bounds__(512) void seq_kernel(
    const float* __restrict__ oWih, const float* __restrict__ oWhh,
    const float* __restrict__ tWih, const float* __restrict__ tWhh,
    const float* __restrict__ fcW, const float* __restrict__ fcb,
    const float* __restrict__ tfcW, const float* __restrict__ tfcb,
    const float* __restrict__ attnW, const float* __restrict__ attnb,
    const float* __restrict__ attncv,
    const int* __restrict__ bn_g,
    const float* __restrict__ opre, const float* __restrict__ tpre,
    float* __restrict__ out) {
    const int j = threadIdx.x;
    const int lane = j & 63;
    const int wave = j >> 6;

    __shared__ float z_lds[512];
    __shared__ float zt_lds[512];
    __shared__ __align__(16) ushort_t fh_pk[128];  // f16-packed o-hidden
    __shared__ __align__(16) ushort_t th_pk[128];  // f16-packed t-hidden
    __shared__ float fcell_lds[128], tcell_lds[128];
    __shared__ float part_lds[10 * 128];
    __shared__ float part_t[128];
    __shared__ float ocol640[512];
    __shared__ float twcol[512 * 11];
    __shared__ float fcw_lds[10 * 128];
    __shared__ float tfcw_lds[128];
    __shared__ float attnW_lds[100];
    __shared__ float attnb_lds[10], attncv_lds[10], fcb_lds[10];
    __shared__ float rn_lds[10];
    __shared__ float tempo_lds[1];
    __shared__ float tfcb_lds[1];
    __shared__ float out_ring[256 * 10];
    __shared__ float sim_ring[256];

    // ---- stage small tensors ----
    for (int k = j; k < 1280; k += 512) fcw_lds[k] = fcW[k];
    if (j < 128) tfcw_lds[j] = tfcW[j];
    if (j < 100) attnW_lds[j] = attnW[j];
    if (j < 10) {
        attnb_lds[j] = attnb[j];
        attncv_lds[j] = attncv[j];
        fcb_lds[j] = fcb[j];
        rn_lds[j] = 0.f;
    }
    if (j < 128) { fcell_lds[j] = 0.f; tcell_lds[j] = 0.f; fh_pk[j] = 0; th_pk[j] = 0; }
    if (j == 0) { tempo_lds[0] = 0.f; tfcb_lds[0] = tfcb[0]; }
    ocol640[j] = oWih[j * 715 + 640];
    twcol[j * 11 + 0] = tWih[j * 467 + 384];
#pragma unroll
    for (int r = 0; r < 10; r++) twcol[j * 11 + 1 + r] = tWih[j * 467 + 393 + r];
    __syncthreads();

    // ---- build fused recurrent row W2[j] = o_Whh[j] + sum_r o_Wih[j][641+r]*fc_W[r]  (f16 packed) ----
    float c1[10];
#pragma unroll
    for (int r = 0; r < 10; r++) c1[r] = oWih[j * 715 + 641 + r];
    float d0 = 0.f;
#pragma unroll
    for (int r = 0; r < 10; r++) d0 += c1[r] * fcb_lds[r];

    uint_t w2pk[64];
    const float* owr = oWhh + j * 128;
#pragma unroll
    for (int q = 0; q < 64; q++) {
        float a = owr[2 * q];
        float b = owr[2 * q + 1];
#pragma unroll
        for (int r = 0; r < 10; r++) {
            a += c1[r] * fcw_lds[r * 128 + 2 * q];
            b += c1[r] * fcw_lds[r * 128 + 2 * q + 1];
        }
        h2v h; h[0] = (_Float16)a; h[1] = (_Float16)b;
        w2pk[q] = __builtin_bit_cast(uint_t, h);
    }
    // t_Whh row j, f32 -> f16 packed
    uint_t tpk[64];
    const float* twr = tWhh + j * 128;
#pragma unroll
    for (int q = 0; q < 64; q++) {
        h2v h; h[0] = (_Float16)twr[2 * q]; h[1] = (_Float16)twr[2 * q + 1];
        tpk[q] = __builtin_bit_cast(uint_t, h);
    }

    const int b0 = bn_g[0];
    int prev_beat = -1, prev_end = 0;
    float opre_cur = opre[j];
    float tpre_cur = tpre[j];
    int bnraw = bn_g[0];
    __syncthreads();

#pragma unroll 1
    for (int i = 0; i < N_NOTES; ++i) {
        const int cb = bnraw - b0;
        const bool bnd = (cb > prev_beat);
        if (bnd) {
            if (wave == 0) {
                const int L = i - prev_end;
                if (L > 0) {
                    float m = -1e30f;
                    for (int b = lane; b < L; b += 64) m = fmaxf(m, sim_ring[(prev_end + b) & 255]);
#pragma unroll
                    for (int d = 32; d >= 1; d >>= 1) m = fmaxf(m, __shfl_xor(m, d));
                    float es = 0.f;
                    float accv[10];
#pragma unroll
                    for (int r = 0; r < 10; r++) accv[r] = 0.f;
                    for (int b = lane; b < L; b += 64) {
                        int idx = (prev_end + b) & 255;
                        float e = __expf(sim_ring[idx] - m);
                        es += e;
#pragma unroll
                        for (int r = 0; r < 10; r++) accv[r] += e * out_ring[idx * 10 + r];
                    }
#pragma unroll
                    for (int d = 32; d >= 1; d >>= 1) {
                        es += __shfl_xor(es, d);
#pragma unroll
                        for (int r = 0; r < 10; r++) accv[r] += __shfl_xor(accv[r], d);
                    }
                    float inv = 1.f / fmaxf(es, 1e-20f);
                    if (lane < 10) rn_lds[lane] = accv[lane] * inv;
                } else {
                    if (lane < 10) rn_lds[lane] = 0.f;
                }
            }
            __syncthreads();  // rn visible to all
        }
        // ---- phase 1: preactivation matvecs (all 512 threads) ----
        float opre_nxt = 0.f, tpre_nxt = 0.f;
        int bnraw_nxt = bnraw;
        if (i + 1 < N_NOTES) {
            opre_nxt = opre[(i + 1) * 512 + j];
            tpre_nxt = tpre[(i + 1) * 512 + j];
            bnraw_nxt = bn_g[i + 1];
        }
        const float tempo_old = tempo_lds[0];
        float zo = opre_cur + ocol640[j] * tempo_old;
        if (i == 0) zo -= d0;
        {
            const uint4* fp = (const uint4*)fh_pk;
#pragma unroll
            for (int q = 0; q < 16; q++) {
                uint4 v = fp[q];
                zo = fdot2f(w2pk[4 * q + 0], v.x, zo);
                zo = fdot2f(w2pk[4 * q + 1], v.y, zo);
                zo = fdot2f(w2pk[4 * q + 2], v.z, zo);
                zo = fdot2f(w2pk[4 * q + 3], v.w, zo);
            }
        }
        z_lds[((j & 127) << 2) | (j >> 7)] = zo;
        if (bnd) {
            float zt = tpre_cur + twcol[j * 11] * tempo_old;
#pragma unroll
            for (int r = 0; r < 10; r++) zt += twcol[j * 11 + 1 + r] * rn_lds[r];
            const uint4* tp = (const uint4*)th_pk;
#pragma unroll
            for (int q = 0; q < 16; q++) {
                uint4 v = tp[q];
                zt = fdot2f(tpk[4 * q + 0], v.x, zt);
                zt = fdot2f(tpk[4 * q + 1], v.y, zt);
                zt = fdot2f(tpk[4 * q + 2], v.z, zt);
                zt = fdot2f(tpk[4 * q + 3], v.w, zt);
            }
            zt_lds[((j & 127) << 2) | (j >> 7)] = zt;
        }
        __syncthreads();  // sync1
        // ---- phase 2: gates (threads 0..127) ----
        if (j < 128) {
            float4 zz = *(const float4*)&z_lds[j * 4];
            float c = fcell_lds[j];
            float c2 = sigm(zz.y) * c + sigm(zz.x) * tanhc(zz.z);
            float h2 = sigm(zz.w) * tanhc(c2);
            fcell_lds[j] = c2;
            ((_Float16*)fh_pk)[j] = (_Float16)h2;
#pragma unroll
            for (int r = 0; r < 10; r++) part_lds[r * 128 + j] = fcw_lds[r * 128 + j] * h2;
            if (bnd) {
                float4 zq = *(const float4*)&zt_lds[j * 4];
                float tc = tcell_lds[j];
                float tc2 = sigm(zq.y) * tc + sigm(zq.x) * tanhc(zq.z);
                float th2 = sigm(zq.w) * tanhc(tc2);
                tcell_lds[j] = tc2;
                ((_Float16*)th_pk)[j] = (_Float16)th2;
                part_t[j] = tfcw_lds[j] * th2;
            }
        }
        __syncthreads();  // sync2
        // ---- phase 3: fc / tempo / sim / outputs (wave 0) ----
        if (wave == 0) {
            float p[10];
#pragma unroll
            for (int r = 0; r < 10; r++) p[r] = part_lds[r * 128 + lane] + part_lds[r * 128 + 64 + lane];
#pragma unroll
            for (int d = 32; d >= 1; d >>= 1) {
#pragma unroll
                for (int r = 0; r < 10; r++) p[r] += __shfl_xor(p[r], d);
            }
            float ofc[10];
#pragma unroll
            for (int r = 0; r < 10; r++) ofc[r] = p[r] + fcb_lds[r];
            float tempo_out = tempo_old;
            if (bnd) {
                float q = part_t[lane] + part_t[lane + 64];
#pragma unroll
                for (int d = 32; d >= 1; d >>= 1) q += __shfl_xor(q, d);
                tempo_out = q + tfcb_lds[0];
            }
            float sim = 0.f;
            if (lane < 10) {
                float a = attnb_lds[lane];
#pragma unroll
                for (int c2 = 0; c2 < 10; c2++) a += attnW_lds[lane * 10 + c2] * ofc[c2];
                sim = tanhc(a) * attncv_lds[lane];
            }
#pragma unroll
            for (int d = 8; d >= 1; d >>= 1) sim += __shfl_xor(sim, d);
            const int ri_ = i & 255;
            if (lane < 10) {
                out_ring[ri_ * 10 + lane] = ofc[lane];
                out[i * 11 + 1 + lane] = ofc[lane];
            }
            if (lane == 0) {
                sim_ring[ri_] = sim;
                out[i * 11] = tempo_out;
                if (bnd) tempo_lds[0] = tempo_out;
            }
        }
        if (bnd) { prev_end = i; prev_beat = cb; }
        opre_cur = opre_nxt;
        tpre_cur = tpre_nxt;
        bnraw = bnraw_nxt;
        if (bnd) __syncthreads();  // make tempo update visible before next phase 1
    }
}

extern "C" void kernel_launch(void* const* d_in, const int* in_sizes, int n_in,
                              void* d_out, int out_size, void* d_ws, size_t ws_size,
                              hipStream_t stream) {
    (void)in_sizes; (void)n_in; (void)out_size; (void)ws_size;
    const float* ne     = (const float*)d_in[0];
    const float* be     = (const float*)d_in[1];
    const float* me     = (const float*)d_in[2];
    const float* ri     = (const float*)d_in[3];
    const float* perf   = (const float*)d_in[4];
    const int*   bn     = (const int*)d_in[5];
    const int*   mn     = (const int*)d_in[6];
    const float* expW   = (const float*)d_in[7];
    const float* expb   = (const float*)d_in[8];
    const float* tWih   = (const float*)d_in[9];
    const float* tWhh   = (const float*)d_in[10];
    const float* tbih   = (const float*)d_in[11];
    const float* tbhh   = (const float*)d_in[12];
    const float* tfcW   = (const float*)d_in[13];
    const float* tfcb   = (const float*)d_in[14];
    const float* attnW  = (const float*)d_in[15];
    const float* attnb  = (const float*)d_in[16];
    const float* attncv = (const float*)d_in[17];
    const float* oWih   = (const float*)d_in[18];
    const float* oWhh   = (const float*)d_in[19];
    const float* obih   = (const float*)d_in[20];
    const float* obhh   = (const float*)d_in[21];
    const float* fcW    = (const float*)d_in[22];
    const float* fcb    = (const float*)d_in[23];

    float* pz   = (float*)d_ws;
    float* opre = pz + 64;
    float* tpre = opre + N_NOTES * 512;
    float* out  = (float*)d_out;

    pz_kernel<<<1, 64, 0, stream>>>(expW, expb, perf, pz);
    opre_kernel<<<N_NOTES, 512, 0, stream>>>(oWih, obih, obhh, ne, be, me, fcb, pz, bn, mn, opre);
    tpre_kernel<<<N_NOTES, 512, 0, stream>>>(tWih, tbih, tbhh, be, me, ri, pz, bn, mn, tpre);
    seq_kernel<<<1, 512, 0, stream>>>(oWih, oWhh, tWih, tWhh, fcW, fcb, tfcW, tfcb,
                                      attnW, attnb, attncv, bn, opre, tpre, out);
}

// Round 3
// 4446.458 us; speedup vs baseline: 1.2224x; 1.2224x over previous
//
#include <hip/hip_runtime.h>
#include <hip/hip_bf16.h>

typedef unsigned short ushort_t;
typedef unsigned int uint_t;
typedef _Float16 h2v __attribute__((ext_vector_type(2)));

#define N_NOTES 2000

__device__ __forceinline__ float sigm(float x) { return 1.0f / (1.0f + __expf(-x)); }
__device__ __forceinline__ float tanhc(float x) {
    x = fminf(fmaxf(x, -15.f), 15.f);
    float e = __expf(2.f * x);
    return (e - 1.f) / (e + 1.f);
}

#if __has_builtin(__builtin_amdgcn_fdot2)
__device__ __forceinline__ float fdot2f(uint_t a, uint_t b, float c) {
    return __builtin_amdgcn_fdot2(__builtin_bit_cast(h2v, a), __builtin_bit_cast(h2v, b), c, false);
}
#else
__device__ __forceinline__ float fdot2f(uint_t a, uint_t b, float c) {
    h2v x = __builtin_bit_cast(h2v, a), y = __builtin_bit_cast(h2v, b);
    return c + (float)x[0] * (float)y[0] + (float)x[1] * (float)y[1];
}
#endif

// Raw barrier: lgkm-only drain (keeps global prefetch loads in flight across it).
#define BAR() do { \
    asm volatile("s_waitcnt lgkmcnt(0)" ::: "memory"); \
    __builtin_amdgcn_s_barrier(); \
    asm volatile("" ::: "memory"); \
} while (0)

// ---------------- perform_z = relu(exp_W @ perf + exp_b) ----------------
__global__ __launch_bounds__(64) void pz_kernel(const float* __restrict__ expW,
                                                const float* __restrict__ expb,
                                                const float* __restrict__ perf,
                                                float* __restrict__ pz) {
    int t = threadIdx.x;
    float acc = expb[t];
#pragma unroll
    for (int k = 0; k < 16; k++) acc += expW[t * 16 + k] * perf[k];
    pz[t] = fmaxf(acc, 0.f);
}

// ---------------- opre: 16 notes per block, weight row streamed once per 16 notes ----------------
__global__ __launch_bounds__(512, 2) void opre_kernel(
    const float* __restrict__ oWih, const float* __restrict__ obih, const float* __restrict__ obhh,
    const float* __restrict__ ne, const float* __restrict__ be, const float* __restrict__ me,
    const float* __restrict__ fcb, const float* __restrict__ pz,
    const int* __restrict__ bn, const int* __restrict__ mn, float* __restrict__ opre) {
    const int i0 = blockIdx.x * 16;
    const int j = threadIdx.x;
    __shared__ float xs[16][256];
    __shared__ float xm[16][128];
    __shared__ float pz_l[64];
    __shared__ float fcb_l[10];
    if (j < 64) pz_l[j] = pz[j];
    if (j < 10) fcb_l[j] = fcb[j];
    const int bn0 = bn[0], mn0 = mn[0];
    __syncthreads();
    const float* w = oWih + j * 715;
    float tail = obih[j] + obhh[j];
#pragma unroll
    for (int r = 0; r < 10; r++) tail += w[641 + r] * fcb_l[r];
#pragma unroll 8
    for (int k = 0; k < 64; k++) tail += w[651 + k] * pz_l[k];
    float acc[16];
#pragma unroll
    for (int m = 0; m < 16; m++) acc[m] = tail;
    // segment 1: ne (cols 0..255)
    for (int t = j; t < 16 * 256; t += 512) xs[t >> 8][t & 255] = ne[i0 * 256 + t];
    __syncthreads();
#pragma unroll 4
    for (int k = 0; k < 256; k++) {
        float wv = w[k];
#pragma unroll
        for (int m = 0; m < 16; m++) acc[m] += wv * xs[m][k];
    }
    __syncthreads();
    // segment 2: be[cb] (cols 256..511)
    for (int t = j; t < 16 * 256; t += 512) {
        int m = t >> 8, k = t & 255;
        xs[m][k] = be[(bn[i0 + m] - bn0) * 256 + k];
    }
    __syncthreads();
#pragma unroll 4
    for (int k = 0; k < 256; k++) {
        float wv = w[256 + k];
#pragma unroll
        for (int m = 0; m < 16; m++) acc[m] += wv * xs[m][k];
    }
    __syncthreads();
    // segment 3: me[cm] (cols 512..639)
    for (int t = j; t < 16 * 128; t += 512) {
        int m = t >> 7, k = t & 127;
        xm[m][k] = me[(mn[i0 + m] - mn0) * 128 + k];
    }
    __syncthreads();
#pragma unroll 4
    for (int k = 0; k < 128; k++) {
        float wv = w[512 + k];
#pragma unroll
        for (int m = 0; m < 16; m++) acc[m] += wv * xm[m][k];
    }
#pragma unroll
    for (int m = 0; m < 16; m++) opre[(i0 + m) * 512 + j] = acc[m];
}

// ---------------- tpre: same structure (computed for all notes) ----------------
__global__ __launch_bounds__(512, 2) void tpre_kernel(
    const float* __restrict__ tWih, const float* __restrict__ tbih, const float* __restrict__ tbhh,
    const float* __restrict__ be, const float* __restrict__ me, const float* __restrict__ ri,
    const float* __restrict__ pz, const int* __restrict__ bn, const int* __restrict__ mn,
    float* __restrict__ tpre) {
    const int i0 = blockIdx.x * 16;
    const int j = threadIdx.x;
    __shared__ float xs[16][256];
    __shared__ float xm[16][128];
    __shared__ float xr[16][8];
    __shared__ float pz_l[64];
    if (j < 64) pz_l[j] = pz[j];
    const int bn0 = bn[0], mn0 = mn[0];
    __syncthreads();
    const float* w = tWih + j * 467;
    float tail = tbih[j] + tbhh[j];
#pragma unroll 8
    for (int k = 0; k < 64; k++) tail += w[403 + k] * pz_l[k];
    float acc[16];
#pragma unroll
    for (int m = 0; m < 16; m++) acc[m] = tail;
    // segment 1: be[cb] (cols 0..255)
    for (int t = j; t < 16 * 256; t += 512) {
        int m = t >> 8, k = t & 255;
        xs[m][k] = be[(bn[i0 + m] - bn0) * 256 + k];
    }
    if (j < 128) {
        int m = j >> 3, k = j & 7;
        xr[m][k] = ri[(bn[i0 + m] - bn0) * 8 + k];
    }
    __syncthreads();
#pragma unroll 4
    for (int k = 0; k < 256; k++) {
        float wv = w[k];
#pragma unroll
        for (int m = 0; m < 16; m++) acc[m] += wv * xs[m][k];
    }
    // ri segment (cols 385..392)
#pragma unroll
    for (int k = 0; k < 8; k++) {
        float wv = w[385 + k];
#pragma unroll
        for (int m = 0; m < 16; m++) acc[m] += wv * xr[m][k];
    }
    __syncthreads();
    // me segment (cols 256..383)
    for (int t = j; t < 16 * 128; t += 512) {
        int m = t >> 7, k = t & 127;
        xm[m][k] = me[(mn[i0 + m] - mn0) * 128 + k];
    }
    __syncthreads();
#pragma unroll 4
    for (int k = 0; k < 128; k++) {
        float wv = w[256 + k];
#pragma unroll
        for (int m = 0; m < 16; m++) acc[m] += wv * xm[m][k];
    }
#pragma unroll
    for (int m = 0; m < 16; m++) tpre[(i0 + m) * 512 + j] = acc[m];
}

// ---------------- the 2000-step serial scan: one 512-thread workgroup ----------------
__global__ __launch_bounds__(512, 2) void seq_kernel(
    const float* __restrict__ oWih, const float* __restrict__ oWhh,
    const float* __restrict__ tWih, const float* __restrict__ tWhh,
    const float* __restrict__ fcW, const float* __restrict__ fcb,
    const float* __restrict__ tfcW, const float* __restrict__ tfcb,
    const float* __restrict__ attnW, const float* __restrict__ attnb,
    const float* __restrict__ attncv,
    const int* __restrict__ bn_g,
    const float* __restrict__ opre, const float* __restrict__ tpre,
    float* __restrict__ out) {
    const int j = threadIdx.x;
    const int lane = j & 63;

    __shared__ float z_lds[512];            // [gate*128 + unit] == row j
    __shared__ float zt_lds[512];
    __shared__ __align__(16) uint_t fh_pk[64];   // uint q = f16{h[2q], h[2q+1]}
    __shared__ __align__(16) uint_t th_pk[64];
    __shared__ float ocol640[512];
    __shared__ float twcol_t[11 * 512];     // [c][j] transposed: conflict-free
    __shared__ float fcw_lds[10 * 128];
    __shared__ float attnW_lds[100];
    __shared__ float attnb_lds[10], attncv_lds[10], fcb_lds[10];
    __shared__ float rn_lds[10];
    __shared__ float tempo_lds[1];
    __shared__ float out_ring[256 * 10];
    __shared__ float sim_ring[256];

    // ---- stage small tensors ----
    for (int k = j; k < 1280; k += 512) fcw_lds[k] = fcW[k];
    if (j < 100) attnW_lds[j] = attnW[j];
    if (j < 10) {
        attnb_lds[j] = attnb[j];
        attncv_lds[j] = attncv[j];
        fcb_lds[j] = fcb[j];
        rn_lds[j] = 0.f;
    }
    if (j < 64) { fh_pk[j] = 0; th_pk[j] = 0; }
    if (j == 0) tempo_lds[0] = 0.f;
    ocol640[j] = oWih[j * 715 + 640];
    twcol_t[0 * 512 + j] = tWih[j * 467 + 384];
#pragma unroll
    for (int r = 0; r < 10; r++) twcol_t[(1 + r) * 512 + j] = tWih[j * 467 + 393 + r];
    __syncthreads();

    // ---- fused recurrent row W2[j] = o_Whh[j] + sum_r o_Wih[j][641+r]*fc_W[r]  (f16 packed) ----
    float c1[10];
#pragma unroll
    for (int r = 0; r < 10; r++) c1[r] = oWih[j * 715 + 641 + r];
    float d0 = 0.f;
#pragma unroll
    for (int r = 0; r < 10; r++) d0 += c1[r] * fcb_lds[r];

    uint_t w2pk[64];
    const float* owr = oWhh + j * 128;
#pragma unroll
    for (int q = 0; q < 64; q++) {
        float a = owr[2 * q];
        float b = owr[2 * q + 1];
#pragma unroll
        for (int r = 0; r < 10; r++) {
            a += c1[r] * fcw_lds[r * 128 + 2 * q];
            b += c1[r] * fcw_lds[r * 128 + 2 * q + 1];
        }
        h2v h; h[0] = (_Float16)a; h[1] = (_Float16)b;
        w2pk[q] = __builtin_bit_cast(uint_t, h);
    }
    uint_t tpk[64];
    const float* twr = tWhh + j * 128;
#pragma unroll
    for (int q = 0; q < 64; q++) {
        h2v h; h[0] = (_Float16)twr[2 * q]; h[1] = (_Float16)twr[2 * q + 1];
        tpk[q] = __builtin_bit_cast(uint_t, h);
    }

    // ---- per-lane epilogue constants (wave 0 uses; cheap regs for all) ----
    float fcwA[10], fcwB[10];
#pragma unroll
    for (int r = 0; r < 10; r++) {
        fcwA[r] = fcw_lds[r * 128 + 2 * lane];
        fcwB[r] = fcw_lds[r * 128 + 2 * lane + 1];
    }
    const float tfcwA = tfcW[2 * lane], tfcwB = tfcW[2 * lane + 1];
    const float tfcb_s = tfcb[0];

    // ---- recurrence state ----
    float fc0 = 0.f, fc1 = 0.f, tc0 = 0.f, tc1 = 0.f;  // cell states (wave-0 lanes)
    float tempo_cur = 0.f;                              // wave-0 lanes
    int prev_end = 0;                                   // wave-0 lanes
    int bn_cur = bn_g[0];
    int bn_nxt = (N_NOTES > 1) ? bn_g[1] : bn_cur;
    bool bnd_cur = true;
    float opre_cur = opre[j];
    float tpre_cur = tpre[j];
    __syncthreads();

#pragma unroll 1
    for (int i = 0; i < N_NOTES; ++i) {
        const bool bnd_nxt = (bn_nxt > bn_cur);
        // ---- prefetch (spans the whole step; raw barriers don't drain vmcnt) ----
        float opre_nxt = 0.f, tpre_nxt = 0.f;
        int bn_nxt2 = bn_nxt;
        if (i + 1 < N_NOTES) {
            opre_nxt = opre[(i + 1) * 512 + j];
            if (bnd_nxt) tpre_nxt = tpre[(i + 1) * 512 + j];
            if (i + 2 < N_NOTES) bn_nxt2 = bn_g[i + 2];
        }
        // ---- phase 1: preactivation matvecs (all 512 threads) ----
        const float tempo_old = tempo_lds[0];
        float zb = opre_cur + ocol640[j] * tempo_old;
        if (i == 0) zb -= d0;
        {
            const uint4* fp = (const uint4*)fh_pk;
            float a0 = zb, a1 = 0.f, a2 = 0.f, a3 = 0.f;
#pragma unroll
            for (int q = 0; q < 16; q++) {
                uint4 v = fp[q];
                a0 = fdot2f(w2pk[4 * q + 0], v.x, a0);
                a1 = fdot2f(w2pk[4 * q + 1], v.y, a1);
                a2 = fdot2f(w2pk[4 * q + 2], v.z, a2);
                a3 = fdot2f(w2pk[4 * q + 3], v.w, a3);
            }
            z_lds[j] = (a0 + a1) + (a2 + a3);
        }
        if (bnd_cur) {
            float zt = tpre_cur + twcol_t[j] * tempo_old;
#pragma unroll
            for (int r = 0; r < 10; r++) zt += twcol_t[(1 + r) * 512 + j] * rn_lds[r];
            const uint4* tp = (const uint4*)th_pk;
            float a0 = zt, a1 = 0.f, a2 = 0.f, a3 = 0.f;
#pragma unroll
            for (int q = 0; q < 16; q++) {
                uint4 v = tp[q];
                a0 = fdot2f(tpk[4 * q + 0], v.x, a0);
                a1 = fdot2f(tpk[4 * q + 1], v.y, a1);
                a2 = fdot2f(tpk[4 * q + 2], v.z, a2);
                a3 = fdot2f(tpk[4 * q + 3], v.w, a3);
            }
            zt_lds[j] = (a0 + a1) + (a2 + a3);
        }
        BAR();  // sync1: z (and zt) visible to wave 0
        // ---- phase 2+3: wave 0 does gates, fc, sim, tempo, rings, next-step attention ----
        if (j < 64) {
            const int u0 = 2 * lane;
            float2 zi = *(const float2*)&z_lds[u0];
            float2 zf = *(const float2*)&z_lds[128 + u0];
            float2 zg = *(const float2*)&z_lds[256 + u0];
            float2 zo = *(const float2*)&z_lds[384 + u0];
            fc0 = sigm(zf.x) * fc0 + sigm(zi.x) * tanhc(zg.x);
            fc1 = sigm(zf.y) * fc1 + sigm(zi.y) * tanhc(zg.y);
            float h0 = sigm(zo.x) * tanhc(fc0);
            float h1 = sigm(zo.y) * tanhc(fc1);
            { h2v h; h[0] = (_Float16)h0; h[1] = (_Float16)h1;
              fh_pk[lane] = __builtin_bit_cast(uint_t, h); }
            float p[10];
#pragma unroll
            for (int r = 0; r < 10; r++) p[r] = fcwA[r] * h0 + fcwB[r] * h1;
            float q = 0.f;
            if (bnd_cur) {
                float2 ti = *(const float2*)&zt_lds[u0];
                float2 tf = *(const float2*)&zt_lds[128 + u0];
                float2 tg = *(const float2*)&zt_lds[256 + u0];
                float2 to = *(const float2*)&zt_lds[384 + u0];
                tc0 = sigm(tf.x) * tc0 + sigm(ti.x) * tanhc(tg.x);
                tc1 = sigm(tf.y) * tc1 + sigm(ti.y) * tanhc(tg.y);
                float g0 = sigm(to.x) * tanhc(tc0);
                float g1 = sigm(to.y) * tanhc(tc1);
                { h2v h; h[0] = (_Float16)g0; h[1] = (_Float16)g1;
                  th_pk[lane] = __builtin_bit_cast(uint_t, h); }
                q = tfcwA * g0 + tfcwB * g1;
            }
            // butterfly reduce: 10 fc partials (+1 tempo partial on bnd)
#pragma unroll
            for (int d = 32; d >= 1; d >>= 1) {
#pragma unroll
                for (int r = 0; r < 10; r++) p[r] += __shfl_xor(p[r], d);
                if (bnd_cur) q += __shfl_xor(q, d);
            }
            float ofc[10];
#pragma unroll
            for (int r = 0; r < 10; r++) ofc[r] = p[r] + fcb_lds[r];
            if (bnd_cur) {
                tempo_cur = q + tfcb_s;
                if (lane == 0) tempo_lds[0] = tempo_cur;
            }
            // sim_i = tanh(attnW @ ofc + attnb) . attncv
            float sim = 0.f;
            if (lane < 10) {
                float a = attnb_lds[lane];
#pragma unroll
                for (int c = 0; c < 10; c++) a += attnW_lds[lane * 10 + c] * ofc[c];
                sim = tanhc(a) * attncv_lds[lane];
            }
#pragma unroll
            for (int d = 8; d >= 1; d >>= 1) sim += __shfl_xor(sim, d);
            // outputs + ring
            float vsel = 0.f;
#pragma unroll
            for (int r = 0; r < 10; r++) vsel = (lane == r) ? ofc[r] : vsel;
            const int ri_ = i & 255;
            if (lane < 10) {
                out_ring[ri_ * 10 + lane] = vsel;
                out[i * 11 + 1 + lane] = vsel;
            }
            if (lane == 0) {
                sim_ring[ri_] = sim;
                out[i * 11] = tempo_cur;
            }
            if (bnd_cur) prev_end = i;
            // ---- attention for NEXT step (wave-0-local ring data) ----
            if (bnd_nxt && (i + 1 < N_NOTES)) {
                asm volatile("s_waitcnt lgkmcnt(0)" ::: "memory");  // ring writes visible in-wave
                const int L = i - prev_end + 1;
                float m = -1e30f;
                for (int b = lane; b < L; b += 64) m = fmaxf(m, sim_ring[(prev_end + b) & 255]);
#pragma unroll
                for (int d = 32; d >= 1; d >>= 1) m = fmaxf(m, __shfl_xor(m, d));
                float es = 0.f;
                float accv[10];
#pragma unroll
                for (int r = 0; r < 10; r++) accv[r] = 0.f;
                for (int b = lane; b < L; b += 64) {
                    int idx = (prev_end + b) & 255;
                    float e = __expf(sim_ring[idx] - m);
                    es += e;
#pragma unroll
                    for (int r = 0; r < 10; r++) accv[r] += e * out_ring[idx * 10 + r];
                }
#pragma unroll
                for (int d = 32; d >= 1; d >>= 1) {
                    es += __shfl_xor(es, d);
#pragma unroll
                    for (int r = 0; r < 10; r++) accv[r] += __shfl_xor(accv[r], d);
                }
                float inv = 1.f / fmaxf(es, 1e-20f);
                if (lane < 10) rn_lds[lane] = accv[lane] * inv;
            }
        }
        BAR();  // sync_end: fh/th/tempo/rn visible to all for next phase 1
        // rotate prefetch
        opre_cur = opre_nxt;
        tpre_cur = tpre_nxt;
        bn_cur = bn_nxt;
        bn_nxt = bn_nxt2;
        bnd_cur = bnd_nxt;
    }
}

extern "C" void kernel_launch(void* const* d_in, const int* in_sizes, int n_in,
                              void* d_out, int out_size, void* d_ws, size_t ws_size,
                              hipStream_t stream) {
    (void)in_sizes; (void)n_in; (void)out_size; (void)ws_size;
    const float* ne     = (const float*)d_in[0];
    const float* be     = (const float*)d_in[1];
    const float* me     = (const float*)d_in[2];
    const float* ri     = (const float*)d_in[3];
    const float* perf   = (const float*)d_in[4];
    const int*   bn     = (const int*)d_in[5];
    const int*   mn     = (const int*)d_in[6];
    const float* expW   = (const float*)d_in[7];
    const float* expb   = (const float*)d_in[8];
    const float* tWih   = (const float*)d_in[9];
    const float* tWhh   = (const float*)d_in[10];
    const float* tbih   = (const float*)d_in[11];
    const float* tbhh   = (const float*)d_in[12];
    const float* tfcW   = (const float*)d_in[13];
    const float* tfcb   = (const float*)d_in[14];
    const float* attnW  = (const float*)d_in[15];
    const float* attnb  = (const float*)d_in[16];
    const float* attncv = (const float*)d_in[17];
    const float* oWih   = (const float*)d_in[18];
    const float* oWhh   = (const float*)d_in[19];
    const float* obih   = (const float*)d_in[20];
    const float* obhh   = (const float*)d_in[21];
    const float* fcW    = (const float*)d_in[22];
    const float* fcb    = (const float*)d_in[23];

    float* pz   = (float*)d_ws;
    float* opre = pz + 64;
    float* tpre = opre + N_NOTES * 512;
    float* out  = (float*)d_out;

    pz_kernel<<<1, 64, 0, stream>>>(expW, expb, perf, pz);
    opre_kernel<<<N_NOTES / 16, 512, 0, stream>>>(oWih, obih, obhh, ne, be, me, fcb, pz, bn, mn, opre);
    tpre_kernel<<<N_NOTES / 16, 512, 0, stream>>>(tWih, tbih, tbhh, be, me, ri, pz, bn, mn, tpre);
    seq_kernel<<<1, 512, 0, stream>>>(oWih, oWhh, tWih, tWhh, fcW, fcb, tfcW, tfcb,
                                      attnW, attnb, attncv, bn, opre, tpre, out);
}